// Round 4
// baseline (2666.977 us; speedup 1.0000x reference)
//
#include <hip/hip_runtime.h>
#include <hip/hip_bf16.h>
#include <cmath>

// Problem constants
#define N_   128
#define T_   64
#define D_   1024
#define H_   1024
#define G4_  4096   // 4*H
#define KTOT 3072   // D + H + H (segments: x | h | attn)

typedef short bf16x8 __attribute__((ext_vector_type(8)));
typedef float f32x4  __attribute__((ext_vector_type(4)));

__device__ __forceinline__ unsigned short f2bf(float f) {
    union { float f; unsigned int u; } v; v.f = f;
    unsigned int r = (v.u + 0x7FFFu + ((v.u >> 16) & 1u)) >> 16;  // RNE
    return (unsigned short)r;
}

// ---------------------------------------------------------------- prep ----

__global__ void k_convert_x(const float* __restrict__ x, unsigned short* __restrict__ xbf) {
    long i = ((long)blockIdx.x * blockDim.x + threadIdx.x) * 8;
    float4 a = *(const float4*)(x + i);
    float4 b = *(const float4*)(x + i + 4);
    union { unsigned short s[8]; uint4 v; } o;
    o.s[0] = f2bf(a.x); o.s[1] = f2bf(a.y); o.s[2] = f2bf(a.z); o.s[3] = f2bf(a.w);
    o.s[4] = f2bf(b.x); o.s[5] = f2bf(b.y); o.s[6] = f2bf(b.z); o.s[7] = f2bf(b.w);
    *(uint4*)(xbf + i) = o.v;
}

// out[c][ocoff + r] = bf16(in[r][c]); in is R x C (f32), out rows have stride ors.
__global__ void k_transpose(const float* __restrict__ in, unsigned short* __restrict__ out,
                            int R, int C, long ors, long ocoff) {
    __shared__ float tile[32][33];
    int c0 = blockIdx.x * 32, r0 = blockIdx.y * 32;
    int tx = threadIdx.x, ty = threadIdx.y;  // (32, 8)
    for (int yy = ty; yy < 32; yy += 8) {
        int r = r0 + yy, c = c0 + tx;
        if (r < R && c < C) tile[yy][tx] = in[(long)r * C + c];
    }
    __syncthreads();
    for (int yy = ty; yy < 32; yy += 8) {
        int oc = c0 + yy;    // out row  (orig col)
        int orr = r0 + tx;   // out col  (orig row)
        if (oc < C && orr < R) out[(long)oc * ors + ocoff + orr] = f2bf(tile[tx][yy]);
    }
}

// h0[n][j] = mean_p A[n][j][p];  c0 = h0;  also bf16 copy
__global__ void k_h0(const float* __restrict__ A, float* __restrict__ h,
                     float* __restrict__ c, unsigned short* __restrict__ hbf) {
    long id = (long)blockIdx.x * blockDim.x + threadIdx.x;  // 0 .. 128*1024-1
    const float4* ap = (const float4*)(A + id * 16);
    float s = 0.f;
    #pragma unroll
    for (int q = 0; q < 4; q++) { float4 v = ap[q]; s += v.x + v.y + v.z + v.w; }
    float m = s * (1.0f / 16.0f);
    h[id] = m; c[id] = m; hbf[id] = f2bf(m);
}

// ------------------------------------------------------------- per step ----

// scores -> softmax -> attn (fp32). One block (512 thr) per n; A read ONCE,
// rows kept in registers for the weighted-sum pass.
__global__ __launch_bounds__(512)
void k_score(const float* __restrict__ A, const float* __restrict__ h,
             unsigned short* __restrict__ attnbf) {
    int n = blockIdx.x;
    int tid = threadIdx.x;            // 0..511
    int wave = tid >> 6, lane = tid & 63;
    const float* An = A + (long)n * (H_ * 16);
    const float* hn = h + (long)n * H_;

    int h0 = tid * 2;                 // this thread's two H rows
    float4 row[2][4];
    float acc[16];
    #pragma unroll
    for (int p = 0; p < 16; p++) acc[p] = 0.f;
    #pragma unroll
    for (int u = 0; u < 2; u++) {
        float hv = hn[h0 + u];
        const float4* ap = (const float4*)(An + (long)(h0 + u) * 16);
        #pragma unroll
        for (int q = 0; q < 4; q++) {
            float4 v = ap[q];
            row[u][q] = v;
            acc[q*4+0] += hv * v.x; acc[q*4+1] += hv * v.y;
            acc[q*4+2] += hv * v.z; acc[q*4+3] += hv * v.w;
        }
    }
    // wave shuffle reduce (64 lanes)
    #pragma unroll
    for (int off = 32; off > 0; off >>= 1) {
        #pragma unroll
        for (int p = 0; p < 16; p++) acc[p] += __shfl_xor(acc[p], off);
    }
    __shared__ float sred[8][16];
    __shared__ float wsh[16];
    if (lane == 0) {
        #pragma unroll
        for (int p = 0; p < 16; p++) sred[wave][p] = acc[p];
    }
    __syncthreads();
    if (tid < 16) {
        float s = 0.f;
        #pragma unroll
        for (int w = 0; w < 8; w++) s += sred[w][tid];
        wsh[tid] = s * (1.0f / 32.0f);   // /sqrt(H)
    }
    __syncthreads();
    float w[16];
    {
        float m = -1e30f;
        #pragma unroll
        for (int p = 0; p < 16; p++) { w[p] = wsh[p]; m = fmaxf(m, w[p]); }
        float sum = 0.f;
        #pragma unroll
        for (int p = 0; p < 16; p++) { w[p] = expf(w[p] - m); sum += w[p]; }
        float inv = 1.0f / sum;
        #pragma unroll
        for (int p = 0; p < 16; p++) w[p] *= inv;
    }
    #pragma unroll
    for (int u = 0; u < 2; u++) {
        float s = 0.f;
        #pragma unroll
        for (int q = 0; q < 4; q++) {
            float4 v = row[u][q];
            s += w[q*4+0]*v.x + w[q*4+1]*v.y + w[q*4+2]*v.z + w[q*4+3]*v.w;
        }
        attnbf[(long)n * H_ + h0 + u] = f2bf(s);
    }
}

// Fused gate GEMM: act = [xt|h|attn] @ Wt^T + b, then LSTM update.
// grid (64 jt, 4 rt), block 512 = 8 waves.
// wave = ks(2 k-halves) x rs(2 row subtiles) x gp(2 gate pairs):
//   16 rows x 16 jh x 2 gates over K=1536; 48 iters x (1 A + 2 B -> 2 MFMA).
// One LDS reduce round (k-halves) + act exchange, 2 barriers total.
// blockIdx linear b = jt + 64*rt -> XCD = b%8 = jt%8: per-XCD Wt slice (3MB)
// identical every step -> L2-resident; all 4 row-blocks of a jt share one L2.
__global__ __launch_bounds__(512)
void k_step(const unsigned short* __restrict__ xbf,     // [N][T][D]
            const unsigned short* __restrict__ hbf_in,  // [N][H]
            const unsigned short* __restrict__ attnbf,  // [N][H]
            const unsigned short* __restrict__ Wt,      // [4096][3072]
            const float* __restrict__ bvec,             // [4096]
            float* __restrict__ c, float* __restrict__ h,
            unsigned short* __restrict__ hbf_out,
            float* __restrict__ out, int t) {
    int wv   = threadIdx.x >> 6;   // 0..7
    int lane = threadIdx.x & 63;
    int ks = wv & 1;               // k-half
    int rs = (wv >> 1) & 1;        // row subtile
    int gp = wv >> 2;              // gate pair (gates 2gp, 2gp+1)
    int cl = lane & 15;            // MFMA col (jh) / A row within subtile
    int kg = lane >> 4;            // MFMA k-group
    int colbase = blockIdx.x * 16;           // jh base
    int rowbase = blockIdx.y * 32 + rs * 16; // n base of this wave's subtile

    f32x4 acc0 = (f32x4){0.f,0.f,0.f,0.f};
    f32x4 acc1 = (f32x4){0.f,0.f,0.f,0.f};

    int r0 = rowbase + cl;
    int kw = ks * 512 + kg * 8;    // k offset within each 1024-segment
    const unsigned short* a0[3];
    a0[0] = xbf    + ((long)r0 * T_ + t) * D_ + kw;
    a0[1] = hbf_in + (long)r0 * H_          + kw;
    a0[2] = attnbf + (long)r0 * H_          + kw;
    int g0 = gp * 2;
    const unsigned short* b0 = Wt + (long)((g0    ) * 1024 + colbase + cl) * KTOT + kw;
    const unsigned short* b1 = Wt + (long)((g0 + 1) * 1024 + colbase + cl) * KTOT + kw;

    #pragma unroll
    for (int seg = 0; seg < 3; seg++) {
        const unsigned short* ap = a0[seg];
        long koff = (long)seg * 1024;
        #pragma unroll 4
        for (int k0 = 0; k0 < 512; k0 += 32) {
            bf16x8 a   = *(const bf16x8*)(ap + k0);
            bf16x8 bb0 = *(const bf16x8*)(b0 + koff + k0);
            bf16x8 bb1 = *(const bf16x8*)(b1 + koff + k0);
            acc0 = __builtin_amdgcn_mfma_f32_16x16x32_bf16(a, bb0, acc0, 0, 0, 0);
            acc1 = __builtin_amdgcn_mfma_f32_16x16x32_bf16(a, bb1, acc1, 0, 0, 0);
        }
    }

    // ---- k-half reduce (1 round) + act exchange ----
    __shared__ float red[2][2][64][9];   // [rs][gp][lane][8 + pad]
    __shared__ float act[4][32][17];     // [gate][n local][jh + pad]
    if (ks == 1) {
        #pragma unroll
        for (int v = 0; v < 4; v++) {
            red[rs][gp][lane][v]     = acc0[v];
            red[rs][gp][lane][4 + v] = acc1[v];
        }
    }
    __syncthreads();
    if (ks == 0) {
        #pragma unroll
        for (int v = 0; v < 4; v++) {
            float s0 = acc0[v] + red[rs][gp][lane][v];
            float s1 = acc1[v] + red[rs][gp][lane][4 + v];
            int rloc = rs * 16 + kg * 4 + v;   // C/D row = 4*(lane>>4) + reg
            act[g0    ][rloc][cl] = s0;
            act[g0 + 1][rloc][cl] = s1;
        }
    }
    __syncthreads();

    // ---- balanced epilogue: 512 threads x 1 (n, jh) output ----
    int tid  = threadIdx.x;
    int nloc = tid >> 4;        // 0..31
    int jl   = tid & 15;        // 0..15
    int jh = colbase + jl;
    int n  = blockIdx.y * 32 + nloc;
    float xi = act[0][nloc][jl] + bvec[jh];
    float xf = act[1][nloc][jl] + bvec[1024 + jh];
    float xo = act[2][nloc][jl] + bvec[2048 + jh];
    float xg = act[3][nloc][jl] + bvec[3072 + jh];
    float ig = 1.f / (1.f + expf(-xi));
    float fg = 1.f / (1.f + expf(-xf));
    float og = 1.f / (1.f + expf(-xo));
    float gg = tanhf(xg);
    long idx = (long)n * H_ + jh;
    float cn = fg * c[idx] + ig * gg;
    float hn = og * tanhf(cn);
    c[idx] = cn;
    h[idx] = hn;
    hbf_out[idx] = f2bf(hn);
    out[((long)n * T_ + t) * H_ + jh] = hn;
}

// ---------------------------------------------------------------- launch ----

extern "C" void kernel_launch(void* const* d_in, const int* in_sizes, int n_in,
                              void* d_out, int out_size, void* d_ws, size_t ws_size,
                              hipStream_t stream) {
    const float* x     = (const float*)d_in[0];
    const float* A     = (const float*)d_in[1];
    const float* Wx    = (const float*)d_in[2];
    const float* Wh    = (const float*)d_in[3];
    const float* Wattn = (const float*)d_in[4];
    const float* b     = (const float*)d_in[5];
    float* out = (float*)d_out;

    char* ws = (char*)d_ws;
    size_t off = 0;
    auto alloc = [&](size_t bytes) -> void* {
        void* p = ws + off;
        off += (bytes + 255) & ~(size_t)255;
        return p;
    };
    unsigned short* xbf    = (unsigned short*)alloc((size_t)N_ * T_ * D_ * 2);
    unsigned short* Wt     = (unsigned short*)alloc((size_t)G4_ * KTOT * 2);
    float*          hbuf   = (float*)alloc((size_t)N_ * H_ * 4);
    float*          cbuf   = (float*)alloc((size_t)N_ * H_ * 4);
    unsigned short* hbf0   = (unsigned short*)alloc((size_t)N_ * H_ * 2);
    unsigned short* hbf1   = (unsigned short*)alloc((size_t)N_ * H_ * 2);
    unsigned short* attnbf = (unsigned short*)alloc((size_t)N_ * H_ * 2);

    // prep
    k_convert_x<<<dim3((N_ * T_ * D_) / (256 * 8)), dim3(256), 0, stream>>>(x, xbf);
    k_transpose<<<dim3(G4_ / 32, D_ / 32), dim3(32, 8), 0, stream>>>(Wx,    Wt, D_, G4_, (long)KTOT, 0L);
    k_transpose<<<dim3(G4_ / 32, H_ / 32), dim3(32, 8), 0, stream>>>(Wh,    Wt, H_, G4_, (long)KTOT, 1024L);
    k_transpose<<<dim3(G4_ / 32, H_ / 32), dim3(32, 8), 0, stream>>>(Wattn, Wt, H_, G4_, (long)KTOT, 2048L);
    k_h0<<<dim3((N_ * H_) / 256), dim3(256), 0, stream>>>(A, hbuf, cbuf, hbf0);

    // recurrence
    for (int t = 0; t < T_; t++) {
        unsigned short* hin  = (t & 1) ? hbf1 : hbf0;
        unsigned short* hout = (t & 1) ? hbf0 : hbf1;
        k_score<<<dim3(N_), dim3(512), 0, stream>>>(A, hbuf, attnbf);
        k_step<<<dim3(64, 4), dim3(512), 0, stream>>>(xbf, hin, attnbf, Wt, b,
                                                      cbuf, hbuf, hout, out, t);
    }
}